// Round 8
// baseline (416.834 us; speedup 1.0000x reference)
//
#include <hip/hip_runtime.h>
#include <hip/hip_bf16.h>
#include <hip/hip_cooperative_groups.h>

namespace cg = cooperative_groups;

// Non-local block via rank-128 factorization:
//   G~ = g_w x + g_b ; T~ = theta_w x + theta_b ; P~ = phi_w x + phi_b   [128x4096]/batch
//   S''[p][g] = sum_n P~[p][n] G~[g][n]                                  [128x128]/batch
//   W2 = out_w @ S''^T / N                                               [256x128]/batch
//   out = x + W2 @ T~ + out_b
// Preferred: ONE cooperative kernel (grid 512), 6 phases / 5 grid.sync()s —
// eliminates 5 kernel-launch gaps. Fallback (if coop launch unsupported):
// the proven 6-launch path with identical phase bodies.

#define CC   256
#define NSP  4096
#define NB   4
#define KSPLIT 32

typedef __attribute__((ext_vector_type(8))) short bf16x8;
typedef __attribute__((ext_vector_type(4))) float f32x4;

// fp32 region (float offsets from wsf): [4][32][128][128] S'' partials
#define F_WEND 2097152
// bf16 region (ushort offsets from wsh = wsf + F_WEND)
#define H_TT   0                    // [4][4096][128]  TT[n][p] = T~[p][n]
#define H_PG   2097152              // [4][256][4096]  rows 0-127 = G~, 128-255 = P~
#define H_S2   6291456              // [4][128][128]   S'' bf16
#define H_WH   6356992              // [384][256] bf16 weights: g / theta / phi
#define H_W2   6455296              // [4][256][128] bf16 W2

__device__ __forceinline__ unsigned short f2bf(float f) {
  __hip_bfloat16 h = __float2bfloat16(f);
  return __builtin_bit_cast(unsigned short, h);
}
__device__ __forceinline__ uint4 pack8(const unsigned short* h) {
  uint4 u;
  u.x = (unsigned)h[0] | ((unsigned)h[1] << 16);
  u.y = (unsigned)h[2] | ((unsigned)h[3] << 16);
  u.z = (unsigned)h[4] | ((unsigned)h[5] << 16);
  u.w = (unsigned)h[6] | ((unsigned)h[7] << 16);
  return u;
}
// load 8 consecutive fp32, convert RNE -> bf16x8
__device__ __forceinline__ bf16x8 ld_cvt8(const float* __restrict__ p) {
  float4 lo = *(const float4*)p;
  float4 hi = *(const float4*)(p + 4);
  bf16x8 r;
  r[0] = (short)f2bf(lo.x); r[1] = (short)f2bf(lo.y);
  r[2] = (short)f2bf(lo.z); r[3] = (short)f2bf(lo.w);
  r[4] = (short)f2bf(hi.x); r[5] = (short)f2bf(hi.y);
  r[6] = (short)f2bf(hi.z); r[7] = (short)f2bf(hi.w);
  return r;
}

// Wave computes C[64x64] += A[64xK] * B^T[64xK] (bf16 row-major, K contiguous), 1-deep prefetch.
__device__ __forceinline__ void wave_gemm_bt(const unsigned short* __restrict__ A, int pitchA,
                                             const unsigned short* __restrict__ B, int pitchB,
                                             int K, int lane, f32x4 acc[4][4]) {
  int lm = lane & 15, lq = lane >> 4;
  const unsigned short* ap[4];
  const unsigned short* bp[4];
#pragma unroll
  for (int i = 0; i < 4; ++i) {
    ap[i] = A + (size_t)(i * 16 + lm) * pitchA + lq * 8;
    bp[i] = B + (size_t)(i * 16 + lm) * pitchB + lq * 8;
  }
  bf16x8 a0[4], b0[4];
#pragma unroll
  for (int i = 0; i < 4; ++i) {
    a0[i] = *(const bf16x8*)(ap[i]);
    b0[i] = *(const bf16x8*)(bp[i]);
  }
  for (int k = 32; k < K; k += 32) {
    bf16x8 a1[4], b1[4];
#pragma unroll
    for (int i = 0; i < 4; ++i) {
      a1[i] = *(const bf16x8*)(ap[i] + k);
      b1[i] = *(const bf16x8*)(bp[i] + k);
    }
#pragma unroll
    for (int mi = 0; mi < 4; ++mi)
#pragma unroll
      for (int ni = 0; ni < 4; ++ni)
        acc[mi][ni] = __builtin_amdgcn_mfma_f32_16x16x32_bf16(a0[mi], b0[ni], acc[mi][ni], 0, 0, 0);
#pragma unroll
    for (int i = 0; i < 4; ++i) { a0[i] = a1[i]; b0[i] = b1[i]; }
  }
#pragma unroll
  for (int mi = 0; mi < 4; ++mi)
#pragma unroll
    for (int ni = 0; ni < 4; ++ni)
      acc[mi][ni] = __builtin_amdgcn_mfma_f32_16x16x32_bf16(a0[mi], b0[ni], acc[mi][ni], 0, 0, 0);
}

// ================= phase bodies (shared by fused + fallback) =================

// weights fp32 -> bf16 stack [g; theta; phi]; bid < 96
__device__ __forceinline__ void phaseW(int bid, int t,
    const float* __restrict__ g_w, const float* __restrict__ theta_w,
    const float* __restrict__ phi_w, unsigned short* __restrict__ wsh) {
  int idx = (bid * 256 + t) * 4;
  int r = idx >> 8;
  const float* src = (r < 128) ? (g_w + idx)
                   : (r < 256) ? (theta_w + idx - 32768)
                               : (phi_w + idx - 65536);
  float4 v = *(const float4*)src;
  uint2 o;
  o.x = (unsigned)f2bf(v.x) | ((unsigned)f2bf(v.y) << 16);
  o.y = (unsigned)f2bf(v.z) | ((unsigned)f2bf(v.w) << 16);
  *(uint2*)(wsh + H_WH + idx) = o;
}

// fused X-transpose + prefetched single k-sweep, 3 projections; bid < 512
__device__ __forceinline__ void phaseP(int bid, int t,
    const float* __restrict__ g_b, const float* __restrict__ theta_b,
    const float* __restrict__ phi_b, const float* __restrict__ x,
    unsigned short* __restrict__ wsh,
    float (*T)[33], unsigned short* XL, float* biasL) {
  int b = bid >> 7, c = bid & 127;
  if (t < 128) {
    biasL[t]       = g_b[t];
    biasL[128 + t] = theta_b[t];
    biasL[256 + t] = phi_b[t];
  }
  for (int s = 0; s < 4; ++s) {
    int r = t >> 2, j = t & 3;
    const float* xr = x + ((size_t)b * CC + s * 64 + r) * NSP + c * 32 + j * 8;
    float4 f0 = *(const float4*)(xr);
    float4 f1 = *(const float4*)(xr + 4);
    T[r][j * 8 + 0] = f0.x; T[r][j * 8 + 1] = f0.y;
    T[r][j * 8 + 2] = f0.z; T[r][j * 8 + 3] = f0.w;
    T[r][j * 8 + 4] = f1.x; T[r][j * 8 + 5] = f1.y;
    T[r][j * 8 + 6] = f1.z; T[r][j * 8 + 7] = f1.w;
    __syncthreads();
    int nr = t >> 3, j2 = t & 7;
    unsigned short o[8];
#pragma unroll
    for (int i = 0; i < 8; ++i) o[i] = f2bf(T[j2 * 8 + i][nr]);
    int kidx = s * 64 + j2 * 8;
    int sw = (nr & 7) << 3;
    *(uint4*)(XL + ((nr * 256 + kidx) ^ sw)) = pack8(o);
    __syncthreads();
  }

  int w = t >> 6, lane = t & 63;
  int lm = lane & 15, lq = lane >> 4;
  int bsw = (lm & 7) << 3;
  const unsigned short* aw[2];
  int bidx[2];
#pragma unroll
  for (int i = 0; i < 2; ++i)
    aw[i] = wsh + H_WH + (size_t)(w * 32 + i * 16 + lm) * 256 + lq * 8;
#pragma unroll
  for (int j = 0; j < 2; ++j)
    bidx[j] = (j * 16 + lm) * 256 + lq * 8;

  f32x4 ag[2][2] = {}, at2[2][2] = {}, ap2[2][2] = {};
  bf16x8 bb0[2], xg0[2], xt0[2], xp0[2];
#pragma unroll
  for (int j = 0; j < 2; ++j) bb0[j] = *(const bf16x8*)(XL + (bidx[j] ^ bsw));
#pragma unroll
  for (int i = 0; i < 2; ++i) {
    xg0[i] = *(const bf16x8*)(aw[i]);
    xt0[i] = *(const bf16x8*)(aw[i] + 32768);
    xp0[i] = *(const bf16x8*)(aw[i] + 65536);
  }
  for (int k = 32; k < 256; k += 32) {
    bf16x8 bb1[2], xg1[2], xt1[2], xp1[2];
#pragma unroll
    for (int j = 0; j < 2; ++j) bb1[j] = *(const bf16x8*)(XL + ((bidx[j] + k) ^ bsw));
#pragma unroll
    for (int i = 0; i < 2; ++i) {
      xg1[i] = *(const bf16x8*)(aw[i] + k);
      xt1[i] = *(const bf16x8*)(aw[i] + 32768 + k);
      xp1[i] = *(const bf16x8*)(aw[i] + 65536 + k);
    }
#pragma unroll
    for (int mi = 0; mi < 2; ++mi)
#pragma unroll
      for (int ni = 0; ni < 2; ++ni) {
        ag[mi][ni]  = __builtin_amdgcn_mfma_f32_16x16x32_bf16(xg0[mi], bb0[ni], ag[mi][ni], 0, 0, 0);
        at2[mi][ni] = __builtin_amdgcn_mfma_f32_16x16x32_bf16(xt0[mi], bb0[ni], at2[mi][ni], 0, 0, 0);
        ap2[mi][ni] = __builtin_amdgcn_mfma_f32_16x16x32_bf16(xp0[mi], bb0[ni], ap2[mi][ni], 0, 0, 0);
      }
#pragma unroll
    for (int i = 0; i < 2; ++i) {
      bb0[i] = bb1[i]; xg0[i] = xg1[i]; xt0[i] = xt1[i]; xp0[i] = xp1[i];
    }
  }
#pragma unroll
  for (int mi = 0; mi < 2; ++mi)
#pragma unroll
    for (int ni = 0; ni < 2; ++ni) {
      ag[mi][ni]  = __builtin_amdgcn_mfma_f32_16x16x32_bf16(xg0[mi], bb0[ni], ag[mi][ni], 0, 0, 0);
      at2[mi][ni] = __builtin_amdgcn_mfma_f32_16x16x32_bf16(xt0[mi], bb0[ni], at2[mi][ni], 0, 0, 0);
      ap2[mi][ni] = __builtin_amdgcn_mfma_f32_16x16x32_bf16(xp0[mi], bb0[ni], ap2[mi][ni], 0, 0, 0);
    }

  size_t tb = (size_t)b * 524288;
#pragma unroll
  for (int mi = 0; mi < 2; ++mi) {
    int p0 = w * 32 + mi * 16 + lq * 4;
#pragma unroll
    for (int ni = 0; ni < 2; ++ni) {
      int n = c * 32 + ni * 16 + lm;
      unsigned short u0 = f2bf(at2[mi][ni][0] + biasL[128 + p0 + 0]);
      unsigned short u1 = f2bf(at2[mi][ni][1] + biasL[128 + p0 + 1]);
      unsigned short u2 = f2bf(at2[mi][ni][2] + biasL[128 + p0 + 2]);
      unsigned short u3 = f2bf(at2[mi][ni][3] + biasL[128 + p0 + 3]);
      uint2 o;
      o.x = (unsigned)u0 | ((unsigned)u1 << 16);
      o.y = (unsigned)u2 | ((unsigned)u3 << 16);
      *(uint2*)(wsh + H_TT + tb + (size_t)n * 128 + p0) = o;
    }
  }

  __syncthreads();
#pragma unroll
  for (int mi = 0; mi < 2; ++mi)
#pragma unroll
    for (int ni = 0; ni < 2; ++ni) {
      int nl = ni * 16 + lm;
#pragma unroll
      for (int rr = 0; rr < 4; ++rr) {
        int p = w * 32 + mi * 16 + lq * 4 + rr;
        XL[p * 32 + nl]         = f2bf(ag[mi][ni][rr] + biasL[p]);
        XL[(128 + p) * 32 + nl] = f2bf(ap2[mi][ni][rr] + biasL[256 + p]);
      }
    }
  __syncthreads();
  size_t pbo = (size_t)b * 1048576;
#pragma unroll
  for (int r4 = 0; r4 < 4; ++r4) {
    int row = r4 * 64 + (t >> 2);
    int coff = (t & 3) * 8;
    *(uint4*)(wsh + H_PG + pbo + (size_t)row * NSP + c * 32 + coff) =
        *(uint4*)(XL + row * 32 + coff);
  }
}

// split-K S'' partials; bid < 128
__device__ __forceinline__ void phaseS(int bid, int t,
    const unsigned short* __restrict__ wsh, float* __restrict__ wsf) {
  int b = bid >> 5, ks = bid & 31;
  int w = t >> 6, lane = t & 63;
  int lm = lane & 15, lq = lane >> 4;
  int qm = w >> 1, qn = w & 1;
  const unsigned short* A = wsh + H_PG + (size_t)b * 1048576 +
                            (size_t)(128 + qm * 64) * NSP + ks * 128;
  const unsigned short* B = wsh + H_PG + (size_t)b * 1048576 +
                            (size_t)(qn * 64) * NSP + ks * 128;
  f32x4 acc[4][4] = {};
  wave_gemm_bt(A, NSP, B, NSP, 128, lane, acc);
  float* P = wsf + (size_t)(b * KSPLIT + ks) * 16384;
#pragma unroll
  for (int mi = 0; mi < 4; ++mi)
#pragma unroll
    for (int rr = 0; rr < 4; ++rr) {
      int p = qm * 64 + mi * 16 + lq * 4 + rr;
#pragma unroll
      for (int ni = 0; ni < 4; ++ni)
        P[p * 128 + qn * 64 + ni * 16 + lm] = acc[mi][ni][rr];
    }
}

// reduce 32 partials -> S'' bf16; bid < 64
__device__ __forceinline__ void phaseR(int bid, int t,
    const float* __restrict__ wsf, unsigned short* __restrict__ wsh) {
  int b = bid >> 4, e = bid & 15;
  int base = e * 1024 + t * 4;
  const float* PB = wsf + (size_t)b * KSPLIT * 16384;
  float4 s = {0.f, 0.f, 0.f, 0.f};
#pragma unroll
  for (int ks = 0; ks < KSPLIT; ++ks) {
    float4 p = *(const float4*)(PB + (size_t)ks * 16384 + base);
    s.x += p.x; s.y += p.y; s.z += p.z; s.w += p.w;
  }
  uint2 o;
  o.x = (unsigned)f2bf(s.x) | ((unsigned)f2bf(s.y) << 16);
  o.y = (unsigned)f2bf(s.z) | ((unsigned)f2bf(s.w) << 16);
  *(uint2*)(wsh + H_S2 + (size_t)b * 16384 + base) = o;
}

// W2 = out_w @ S''(_bt) / N; bid < 16
__device__ __forceinline__ void phaseW2(int bid, int t,
    unsigned short* __restrict__ wsh, const float* __restrict__ out_w) {
  int b = bid >> 2, is = bid & 3;
  int w = t >> 6, lane = t & 63;
  int lm = lane & 15, lq = lane >> 4;
  const unsigned short* B = wsh + H_S2 + (size_t)b * 16384 + (size_t)(w * 32) * 128;
  f32x4 acc[4][2] = {};
  for (int k = 0; k < 128; k += 32) {
    bf16x8 a[4], bb[2];
#pragma unroll
    for (int i = 0; i < 4; ++i)
      a[i] = ld_cvt8(out_w + (size_t)(is * 64 + i * 16 + lm) * 128 + lq * 8 + k);
#pragma unroll
    for (int j = 0; j < 2; ++j)
      bb[j] = *(const bf16x8*)(B + (size_t)(j * 16 + lm) * 128 + lq * 8 + k);
#pragma unroll
    for (int mi = 0; mi < 4; ++mi)
#pragma unroll
      for (int ni = 0; ni < 2; ++ni)
        acc[mi][ni] = __builtin_amdgcn_mfma_f32_16x16x32_bf16(a[mi], bb[ni], acc[mi][ni], 0, 0, 0);
  }
  const float inv = 1.0f / 4096.0f;
#pragma unroll
  for (int mi = 0; mi < 4; ++mi)
#pragma unroll
    for (int rr = 0; rr < 4; ++rr) {
      int i = is * 64 + mi * 16 + lq * 4 + rr;
#pragma unroll
      for (int ni = 0; ni < 2; ++ni) {
        int p = w * 32 + ni * 16 + lm;
        wsh[H_W2 + (size_t)b * 32768 + (size_t)i * 128 + p] = f2bf(acc[mi][ni][rr] * inv);
      }
    }
}

// stream GEMM tile vb (of 1024 64x64 tiles): out = x + W2 @ TT(_bt) + out_b
__device__ __forceinline__ void phaseD(int vb, int t,
    const unsigned short* __restrict__ wsh, const float* __restrict__ x,
    const float* __restrict__ out_b, float* __restrict__ out) {
  int b = vb >> 8, r8 = vb & 255;
  int rq = r8 >> 6, ct = r8 & 63;
  int w = t >> 6, lane = t & 63;
  int wm = w >> 1, wn = w & 1;
  int lm = lane & 15, lq = lane >> 4;
  int rb = rq * 64 + wm * 32, cb = ct * 64 + wn * 32;
  const unsigned short* A = wsh + H_W2 + (size_t)b * 32768;
  const unsigned short* B = wsh + H_TT + (size_t)b * 524288;
  const unsigned short* ap[2];
  const unsigned short* bp[2];
#pragma unroll
  for (int i = 0; i < 2; ++i) {
    ap[i] = A + (size_t)(rb + i * 16 + lm) * 128 + lq * 8;
    bp[i] = B + (size_t)(cb + i * 16 + lm) * 128 + lq * 8;
  }
  f32x4 acc[2][2] = {};
  bf16x8 a0[2], b0[2];
#pragma unroll
  for (int i = 0; i < 2; ++i) {
    a0[i] = *(const bf16x8*)(ap[i]);
    b0[i] = *(const bf16x8*)(bp[i]);
  }
  for (int k = 32; k < 128; k += 32) {
    bf16x8 a1[2], b1[2];
#pragma unroll
    for (int i = 0; i < 2; ++i) {
      a1[i] = *(const bf16x8*)(ap[i] + k);
      b1[i] = *(const bf16x8*)(bp[i] + k);
    }
#pragma unroll
    for (int mi = 0; mi < 2; ++mi)
#pragma unroll
      for (int ni = 0; ni < 2; ++ni)
        acc[mi][ni] = __builtin_amdgcn_mfma_f32_16x16x32_bf16(a0[mi], b0[ni], acc[mi][ni], 0, 0, 0);
#pragma unroll
    for (int i = 0; i < 2; ++i) { a0[i] = a1[i]; b0[i] = b1[i]; }
  }
#pragma unroll
  for (int mi = 0; mi < 2; ++mi)
#pragma unroll
    for (int ni = 0; ni < 2; ++ni)
      acc[mi][ni] = __builtin_amdgcn_mfma_f32_16x16x32_bf16(a0[mi], b0[ni], acc[mi][ni], 0, 0, 0);

#pragma unroll
  for (int mi = 0; mi < 2; ++mi)
#pragma unroll
    for (int rr = 0; rr < 4; ++rr) {
      int row = rb + mi * 16 + lq * 4 + rr;
      float bi = out_b[row];
#pragma unroll
      for (int ni = 0; ni < 2; ++ni) {
        int col = cb + ni * 16 + lm;
        size_t off = ((size_t)b * CC + row) * NSP + col;
        out[off] = acc[mi][ni][rr] + x[off] + bi;
      }
    }
}

// ================= fused cooperative kernel =================
__global__ __launch_bounds__(256, 2) void fused(
    const float* __restrict__ g_w, const float* __restrict__ theta_w,
    const float* __restrict__ phi_w, const float* __restrict__ out_w,
    const float* __restrict__ g_b, const float* __restrict__ theta_b,
    const float* __restrict__ phi_b, const float* __restrict__ out_b,
    const float* __restrict__ x, float* __restrict__ wsf,
    unsigned short* __restrict__ wsh, float* __restrict__ out) {
  __shared__ float T[64][33];
  __shared__ unsigned short XL[32 * 256];
  __shared__ float biasL[384];
  cg::grid_group grid = cg::this_grid();
  int bid = blockIdx.x, t = threadIdx.x;

  if (bid < 96) phaseW(bid, t, g_w, theta_w, phi_w, wsh);
  grid.sync();
  phaseP(bid, t, g_b, theta_b, phi_b, x, wsh, T, XL, biasL);
  grid.sync();
  if (bid < 128) phaseS(bid, t, wsh, wsf);
  grid.sync();
  if (bid < 64) phaseR(bid, t, wsf, wsh);
  grid.sync();
  if (bid < 16) phaseW2(bid, t, wsh, out_w);
  grid.sync();
  phaseD(bid * 2 + 0, t, wsh, x, out_b, out);
  phaseD(bid * 2 + 1, t, wsh, x, out_b, out);
}

// ================= fallback standalone kernels =================
__global__ __launch_bounds__(256) void kW(const float* __restrict__ g_w,
                                          const float* __restrict__ theta_w,
                                          const float* __restrict__ phi_w,
                                          unsigned short* __restrict__ wsh) {
  phaseW(blockIdx.x, threadIdx.x, g_w, theta_w, phi_w, wsh);
}
__global__ __launch_bounds__(256) void kP(
    const float* __restrict__ g_b, const float* __restrict__ theta_b,
    const float* __restrict__ phi_b, const float* __restrict__ x,
    unsigned short* __restrict__ wsh) {
  __shared__ float T[64][33];
  __shared__ unsigned short XL[32 * 256];
  __shared__ float biasL[384];
  phaseP(blockIdx.x, threadIdx.x, g_b, theta_b, phi_b, x, wsh, T, XL, biasL);
}
__global__ __launch_bounds__(256) void kS(const unsigned short* __restrict__ wsh,
                                          float* __restrict__ wsf) {
  phaseS(blockIdx.x, threadIdx.x, wsh, wsf);
}
__global__ __launch_bounds__(256) void kR(const float* __restrict__ wsf,
                                          unsigned short* __restrict__ wsh) {
  phaseR(blockIdx.x, threadIdx.x, wsf, wsh);
}
__global__ __launch_bounds__(256) void kW2(unsigned short* __restrict__ wsh,
                                           const float* __restrict__ out_w) {
  phaseW2(blockIdx.x, threadIdx.x, wsh, out_w);
}
__global__ __launch_bounds__(256) void kD(const unsigned short* __restrict__ wsh,
                                          const float* __restrict__ x,
                                          const float* __restrict__ out_b,
                                          float* __restrict__ out) {
  phaseD(blockIdx.x, threadIdx.x, wsh, x, out_b, out);
}

extern "C" void kernel_launch(void* const* d_in, const int* in_sizes, int n_in,
                              void* d_out, int out_size, void* d_ws, size_t ws_size,
                              hipStream_t stream) {
  const float* x       = (const float*)d_in[0];
  const float* g_w     = (const float*)d_in[1];
  const float* g_b     = (const float*)d_in[2];
  const float* theta_w = (const float*)d_in[3];
  const float* theta_b = (const float*)d_in[4];
  const float* phi_w   = (const float*)d_in[5];
  const float* phi_b   = (const float*)d_in[6];
  const float* out_w   = (const float*)d_in[7];
  const float* out_b   = (const float*)d_in[8];
  float* wsf = (float*)d_ws;
  unsigned short* wsh = (unsigned short*)(wsf + F_WEND);
  float* out = (float*)d_out;

  void* args[] = {(void*)&g_w, (void*)&theta_w, (void*)&phi_w, (void*)&out_w,
                  (void*)&g_b, (void*)&theta_b, (void*)&phi_b, (void*)&out_b,
                  (void*)&x, (void*)&wsf, (void*)&wsh, (void*)&out};
  hipError_t err = hipLaunchCooperativeKernel((const void*)fused, dim3(512), dim3(256),
                                              args, 0, stream);
  if (err != hipSuccess) {
    // fallback: proven 6-launch path (identical phase bodies)
    kW<<<dim3(96), dim3(256), 0, stream>>>(g_w, theta_w, phi_w, wsh);
    kP<<<dim3(512), dim3(256), 0, stream>>>(g_b, theta_b, phi_b, x, wsh);
    kS<<<dim3(128), dim3(256), 0, stream>>>(wsh, wsf);
    kR<<<dim3(64), dim3(256), 0, stream>>>(wsf, wsh);
    kW2<<<dim3(16), dim3(256), 0, stream>>>(wsh, out_w);
    kD<<<dim3(1024), dim3(256), 0, stream>>>(wsh, x, out_b, out);
  }
}

// Round 9
// 126.378 us; speedup vs baseline: 3.2983x; 3.2983x over previous
//
#include <hip/hip_runtime.h>
#include <hip/hip_bf16.h>

// Non-local block via rank-128 factorization:
//   G~ = g_w x + g_b ; T~ = theta_w x + theta_b ; P~ = phi_w x + phi_b   [128x4096]/batch
//   S''[p][g] = sum_n P~[p][n] G~[g][n]                                  [128x128]/batch
//   W2 = out_w @ S''^T / N                                               [256x128]/batch
//   out = x + W2 @ T~ + out_b
// 6 launches (round-6 configuration — best measured: 125.24 us):
//  kW:  weights fp32 -> bf16 (g/theta/phi stack + out_w)
//  kP:  grid 512 (4b x 128 n-slices of 32): transpose-in-LDS + one k-sweep -> 3 proj;
//       TT (theta transposed), g/phi re-staged -> coalesced PG rows
//  kS:  split-K S'' partials from PG (grid 64, K=256 chunks) -> fp32 partials
//  kR:  reduce 16 partials/batch -> S'' bf16
//  kW2: W2 = out_w @ S''(_bt) / N -> bf16 (grid 16)
//  kD:  LDS-free stream GEMM (grid 512): out = x + W2 @ TT(_bt) + out_b
// NOTE (round 8): cooperative mega-kernel with 5 grid.sync()s measured 332 us —
// grid-wide sync costs ~50-60 us each on 8-XCD MI355X. Do not re-attempt.

#define CC   256
#define NSP  4096
#define NB   4
#define KSPLIT 16

typedef __attribute__((ext_vector_type(8))) short bf16x8;
typedef __attribute__((ext_vector_type(4))) float f32x4;

// fp32 region (float offsets from wsf): [4][16][128][128] S'' partials
#define F_WEND 1048576
// bf16 region (ushort offsets from wsh = wsf + F_WEND)
#define H_TT   0                    // [4][4096][128]  TT[n][p] = T~[p][n]
#define H_PG   2097152              // [4][256][4096]  rows 0-127 = G~, 128-255 = P~
#define H_S2   6291456              // [4][128][128]   S'' bf16
#define H_WH   6356992              // [384][256] bf16 weights: g / theta / phi
#define H_OWH  6455296              // [256][128] bf16 out_w
#define H_W2   6488064              // [4][256][128] bf16 W2

__device__ __forceinline__ unsigned short f2bf(float f) {
  __hip_bfloat16 h = __float2bfloat16(f);
  return __builtin_bit_cast(unsigned short, h);
}
__device__ __forceinline__ uint4 pack8(const unsigned short* h) {
  uint4 u;
  u.x = (unsigned)h[0] | ((unsigned)h[1] << 16);
  u.y = (unsigned)h[2] | ((unsigned)h[3] << 16);
  u.z = (unsigned)h[4] | ((unsigned)h[5] << 16);
  u.w = (unsigned)h[6] | ((unsigned)h[7] << 16);
  return u;
}

// Wave computes C[64x64] += A[64xK] * B^T[64xK] (bf16 row-major, K contiguous), 1-deep prefetch.
__device__ __forceinline__ void wave_gemm_bt(const unsigned short* __restrict__ A, int pitchA,
                                             const unsigned short* __restrict__ B, int pitchB,
                                             int K, int lane, f32x4 acc[4][4]) {
  int lm = lane & 15, lq = lane >> 4;
  const unsigned short* ap[4];
  const unsigned short* bp[4];
#pragma unroll
  for (int i = 0; i < 4; ++i) {
    ap[i] = A + (size_t)(i * 16 + lm) * pitchA + lq * 8;
    bp[i] = B + (size_t)(i * 16 + lm) * pitchB + lq * 8;
  }
  bf16x8 a0[4], b0[4];
#pragma unroll
  for (int i = 0; i < 4; ++i) {
    a0[i] = *(const bf16x8*)(ap[i]);
    b0[i] = *(const bf16x8*)(bp[i]);
  }
  for (int k = 32; k < K; k += 32) {
    bf16x8 a1[4], b1[4];
#pragma unroll
    for (int i = 0; i < 4; ++i) {
      a1[i] = *(const bf16x8*)(ap[i] + k);
      b1[i] = *(const bf16x8*)(bp[i] + k);
    }
#pragma unroll
    for (int mi = 0; mi < 4; ++mi)
#pragma unroll
      for (int ni = 0; ni < 4; ++ni)
        acc[mi][ni] = __builtin_amdgcn_mfma_f32_16x16x32_bf16(a0[mi], b0[ni], acc[mi][ni], 0, 0, 0);
#pragma unroll
    for (int i = 0; i < 4; ++i) { a0[i] = a1[i]; b0[i] = b1[i]; }
  }
#pragma unroll
  for (int mi = 0; mi < 4; ++mi)
#pragma unroll
    for (int ni = 0; ni < 4; ++ni)
      acc[mi][ni] = __builtin_amdgcn_mfma_f32_16x16x32_bf16(a0[mi], b0[ni], acc[mi][ni], 0, 0, 0);
}

// ---- kW: weights fp32 -> bf16: [g; theta; phi] stack + out_w. grid 128 ----
__global__ __launch_bounds__(256) void kW(const float* __restrict__ g_w,
                                          const float* __restrict__ theta_w,
                                          const float* __restrict__ phi_w,
                                          const float* __restrict__ out_w,
                                          unsigned short* __restrict__ wsh) {
  int idx = (blockIdx.x * 256 + threadIdx.x) * 4;   // over 131072 els
  const float* src;
  unsigned short* dst;
  if (idx < 98304) {
    int r = idx >> 8;
    src = (r < 128) ? (g_w + idx)
        : (r < 256) ? (theta_w + idx - 32768)
                    : (phi_w + idx - 65536);
    dst = wsh + H_WH + idx;
  } else {
    src = out_w + (idx - 98304);
    dst = wsh + H_OWH + (idx - 98304);
  }
  float4 v = *(const float4*)src;
  uint2 o;
  o.x = (unsigned)f2bf(v.x) | ((unsigned)f2bf(v.y) << 16);
  o.y = (unsigned)f2bf(v.z) | ((unsigned)f2bf(v.w) << 16);
  *(uint2*)dst = o;
}

// ---- kP: fused X-transpose (LDS) + single-sweep 3 projections ----
// grid 512 = 4 batches x 128 col-slices(32n). ~26 KB LDS -> 2 blocks/CU.
__global__ __launch_bounds__(256) void kP(
    const float* __restrict__ g_b, const float* __restrict__ theta_b,
    const float* __restrict__ phi_b, const float* __restrict__ x,
    unsigned short* __restrict__ wsh) {
  __shared__ float T[64][33];
  __shared__ unsigned short XL[32 * 256];    // [n][k], idx ^= ((n&7)<<3); later Y re-stage
  __shared__ float biasL[384];
  int bid = blockIdx.x;
  int b = bid >> 7, c = bid & 127;
  int t = threadIdx.x;
  if (t < 128) {
    biasL[t]       = g_b[t];
    biasL[128 + t] = theta_b[t];
    biasL[256 + t] = phi_b[t];
  }
  // ---- stage: 4 rounds of 64k x 32n ----
  for (int s = 0; s < 4; ++s) {
    int r = t >> 2, j = t & 3;
    const float* xr = x + ((size_t)b * CC + s * 64 + r) * NSP + c * 32 + j * 8;
    float4 f0 = *(const float4*)(xr);
    float4 f1 = *(const float4*)(xr + 4);
    T[r][j * 8 + 0] = f0.x; T[r][j * 8 + 1] = f0.y;
    T[r][j * 8 + 2] = f0.z; T[r][j * 8 + 3] = f0.w;
    T[r][j * 8 + 4] = f1.x; T[r][j * 8 + 5] = f1.y;
    T[r][j * 8 + 6] = f1.z; T[r][j * 8 + 7] = f1.w;
    __syncthreads();
    int nr = t >> 3, j2 = t & 7;
    unsigned short o[8];
#pragma unroll
    for (int i = 0; i < 8; ++i) o[i] = f2bf(T[j2 * 8 + i][nr]);
    int kidx = s * 64 + j2 * 8;
    int sw = (nr & 7) << 3;
    *(uint4*)(XL + ((nr * 256 + kidx) ^ sw)) = pack8(o);
    __syncthreads();
  }

  // ---- one k-sweep, 3 projections (shared B-frags); wave w owns p-rows [w*32, w*32+32) ----
  int w = t >> 6, lane = t & 63;
  int lm = lane & 15, lq = lane >> 4;
  int bsw = (lm & 7) << 3;
  const unsigned short* aw[2];
  int bidx[2];
#pragma unroll
  for (int i = 0; i < 2; ++i)
    aw[i] = wsh + H_WH + (size_t)(w * 32 + i * 16 + lm) * 256 + lq * 8;
#pragma unroll
  for (int j = 0; j < 2; ++j)
    bidx[j] = (j * 16 + lm) * 256 + lq * 8;

  f32x4 ag[2][2] = {}, at2[2][2] = {}, ap2[2][2] = {};
#pragma unroll 2
  for (int k = 0; k < 256; k += 32) {
    bf16x8 bb[2], xg[2], xt[2], xp[2];
#pragma unroll
    for (int j = 0; j < 2; ++j) bb[j] = *(const bf16x8*)(XL + ((bidx[j] + k) ^ bsw));
#pragma unroll
    for (int i = 0; i < 2; ++i) {
      xg[i] = *(const bf16x8*)(aw[i] + k);
      xt[i] = *(const bf16x8*)(aw[i] + 32768 + k);
      xp[i] = *(const bf16x8*)(aw[i] + 65536 + k);
    }
#pragma unroll
    for (int mi = 0; mi < 2; ++mi)
#pragma unroll
      for (int ni = 0; ni < 2; ++ni) {
        ag[mi][ni]  = __builtin_amdgcn_mfma_f32_16x16x32_bf16(xg[mi], bb[ni], ag[mi][ni], 0, 0, 0);
        at2[mi][ni] = __builtin_amdgcn_mfma_f32_16x16x32_bf16(xt[mi], bb[ni], at2[mi][ni], 0, 0, 0);
        ap2[mi][ni] = __builtin_amdgcn_mfma_f32_16x16x32_bf16(xp[mi], bb[ni], ap2[mi][ni], 0, 0, 0);
      }
  }

  // ---- TT store (theta, transposed, packed uint2) ----
  size_t tb = (size_t)b * 524288;
#pragma unroll
  for (int mi = 0; mi < 2; ++mi) {
    int p0 = w * 32 + mi * 16 + lq * 4;
#pragma unroll
    for (int ni = 0; ni < 2; ++ni) {
      int n = c * 32 + ni * 16 + lm;
      unsigned short u0 = f2bf(at2[mi][ni][0] + biasL[128 + p0 + 0]);
      unsigned short u1 = f2bf(at2[mi][ni][1] + biasL[128 + p0 + 1]);
      unsigned short u2 = f2bf(at2[mi][ni][2] + biasL[128 + p0 + 2]);
      unsigned short u3 = f2bf(at2[mi][ni][3] + biasL[128 + p0 + 3]);
      uint2 o;
      o.x = (unsigned)u0 | ((unsigned)u1 << 16);
      o.y = (unsigned)u2 | ((unsigned)u3 << 16);
      *(uint2*)(wsh + H_TT + tb + (size_t)n * 128 + p0) = o;
    }
  }

  // ---- re-stage g/phi into XL [256 rows][32 n] then coalesced PG store ----
  __syncthreads();                   // all waves done reading XL
#pragma unroll
  for (int mi = 0; mi < 2; ++mi)
#pragma unroll
    for (int ni = 0; ni < 2; ++ni) {
      int nl = ni * 16 + lm;
#pragma unroll
      for (int rr = 0; rr < 4; ++rr) {
        int p = w * 32 + mi * 16 + lq * 4 + rr;
        XL[p * 32 + nl]         = f2bf(ag[mi][ni][rr] + biasL[p]);
        XL[(128 + p) * 32 + nl] = f2bf(ap2[mi][ni][rr] + biasL[256 + p]);
      }
    }
  __syncthreads();
  size_t pbo = (size_t)b * 1048576;
#pragma unroll
  for (int r4 = 0; r4 < 4; ++r4) {
    int row = r4 * 64 + (t >> 2);
    int coff = (t & 3) * 8;
    *(uint4*)(wsh + H_PG + pbo + (size_t)row * NSP + c * 32 + coff) =
        *(uint4*)(XL + row * 32 + coff);
  }
}

// ---- kS: split-K S'' partials. grid = 4 batches x 16 chunks (K=256 each) ----
__global__ __launch_bounds__(256) void kS(const unsigned short* __restrict__ wsh,
                                          float* __restrict__ wsf) {
  int bid = blockIdx.x;
  int b = bid >> 4, ks = bid & 15;
  int t = threadIdx.x, w = t >> 6, lane = t & 63;
  int lm = lane & 15, lq = lane >> 4;
  int qm = w >> 1, qn = w & 1;
  const unsigned short* A = wsh + H_PG + (size_t)b * 1048576 +
                            (size_t)(128 + qm * 64) * NSP + ks * 256;
  const unsigned short* B = wsh + H_PG + (size_t)b * 1048576 +
                            (size_t)(qn * 64) * NSP + ks * 256;
  f32x4 acc[4][4] = {};
  wave_gemm_bt(A, NSP, B, NSP, 256, lane, acc);
  float* P = wsf + (size_t)(b * KSPLIT + ks) * 16384;
#pragma unroll
  for (int mi = 0; mi < 4; ++mi)
#pragma unroll
    for (int rr = 0; rr < 4; ++rr) {
      int p = qm * 64 + mi * 16 + lq * 4 + rr;
#pragma unroll
      for (int ni = 0; ni < 4; ++ni)
        P[p * 128 + qn * 64 + ni * 16 + lm] = acc[mi][ni][rr];
    }
}

// ---- kR: reduce partials -> S'' bf16. grid 64 = 4 batches x 16 slices ----
__global__ __launch_bounds__(256) void kR(const float* __restrict__ wsf,
                                          unsigned short* __restrict__ wsh) {
  int bid = blockIdx.x;
  int b = bid >> 4, e = bid & 15;
  int t = threadIdx.x;
  int base = e * 1024 + t * 4;
  const float* PB = wsf + (size_t)b * KSPLIT * 16384;
  float4 s = {0.f, 0.f, 0.f, 0.f};
#pragma unroll
  for (int ks = 0; ks < KSPLIT; ++ks) {
    float4 p = *(const float4*)(PB + (size_t)ks * 16384 + base);
    s.x += p.x; s.y += p.y; s.z += p.z; s.w += p.w;
  }
  uint2 o;
  o.x = (unsigned)f2bf(s.x) | ((unsigned)f2bf(s.y) << 16);
  o.y = (unsigned)f2bf(s.z) | ((unsigned)f2bf(s.w) << 16);
  *(uint2*)(wsh + H_S2 + (size_t)b * 16384 + base) = o;
}

// ---- kW2: W2[i][p] = sum_g out_w[i][g] S''[p][g] / N. grid 16 = 4b x 4 i-slices ----
__global__ __launch_bounds__(256) void kW2(unsigned short* __restrict__ wsh) {
  int bid = blockIdx.x;
  int b = bid >> 2, is = bid & 3;
  int t = threadIdx.x, w = t >> 6, lane = t & 63;
  int lm = lane & 15, lq = lane >> 4;
  const unsigned short* A = wsh + H_OWH + (size_t)(is * 64) * 128;     // out_w rows i
  const unsigned short* B = wsh + H_S2 + (size_t)b * 16384 + (size_t)(w * 32) * 128;  // S'' rows p
  f32x4 acc[4][2] = {};
  for (int k = 0; k < 128; k += 32) {
    bf16x8 a[4], bb[2];
#pragma unroll
    for (int i = 0; i < 4; ++i)
      a[i] = *(const bf16x8*)(A + (size_t)(i * 16 + lm) * 128 + lq * 8 + k);
#pragma unroll
    for (int j = 0; j < 2; ++j)
      bb[j] = *(const bf16x8*)(B + (size_t)(j * 16 + lm) * 128 + lq * 8 + k);
#pragma unroll
    for (int mi = 0; mi < 4; ++mi)
#pragma unroll
      for (int ni = 0; ni < 2; ++ni)
        acc[mi][ni] = __builtin_amdgcn_mfma_f32_16x16x32_bf16(a[mi], bb[ni], acc[mi][ni], 0, 0, 0);
  }
  const float inv = 1.0f / 4096.0f;
#pragma unroll
  for (int mi = 0; mi < 4; ++mi)
#pragma unroll
    for (int rr = 0; rr < 4; ++rr) {
      int i = is * 64 + mi * 16 + lq * 4 + rr;
#pragma unroll
      for (int ni = 0; ni < 2; ++ni) {
        int p = w * 32 + ni * 16 + lm;
        wsh[H_W2 + (size_t)b * 32768 + (size_t)i * 128 + p] = f2bf(acc[mi][ni][rr] * inv);
      }
    }
}

// ---- kD: LDS-free stream GEMM: out = x + W2 @ TT(_bt) + out_b. grid 512 ----
__global__ __launch_bounds__(256) void kD(const unsigned short* __restrict__ wsh,
                                          const float* __restrict__ x,
                                          const float* __restrict__ out_b,
                                          float* __restrict__ out) {
  int bid = blockIdx.x;
  int b = bid >> 7, r7 = bid & 127;
  int tm = r7 >> 6, tn = r7 & 63;
  int t = threadIdx.x, w = t >> 6, lane = t & 63;
  int wm = w >> 1, wn = w & 1;
  int lm = lane & 15, lq = lane >> 4;
  int rb = tm * 128 + wm * 64, cb = tn * 64 + wn * 32;
  const unsigned short* A = wsh + H_W2 + (size_t)b * 32768;
  const unsigned short* B = wsh + H_TT + (size_t)b * 524288;
  const unsigned short* ap[4];
  const unsigned short* bp[2];
#pragma unroll
  for (int i = 0; i < 4; ++i)
    ap[i] = A + (size_t)(rb + i * 16 + lm) * 128 + lq * 8;
#pragma unroll
  for (int j = 0; j < 2; ++j)
    bp[j] = B + (size_t)(cb + j * 16 + lm) * 128 + lq * 8;

  f32x4 acc[4][2] = {};
  bf16x8 a0[4], b0[2];
#pragma unroll
  for (int i = 0; i < 4; ++i) a0[i] = *(const bf16x8*)(ap[i]);
#pragma unroll
  for (int j = 0; j < 2; ++j) b0[j] = *(const bf16x8*)(bp[j]);
  for (int k = 32; k < 128; k += 32) {
    bf16x8 a1[4], b1[2];
#pragma unroll
    for (int i = 0; i < 4; ++i) a1[i] = *(const bf16x8*)(ap[i] + k);
#pragma unroll
    for (int j = 0; j < 2; ++j) b1[j] = *(const bf16x8*)(bp[j] + k);
#pragma unroll
    for (int mi = 0; mi < 4; ++mi)
#pragma unroll
      for (int ni = 0; ni < 2; ++ni)
        acc[mi][ni] = __builtin_amdgcn_mfma_f32_16x16x32_bf16(a0[mi], b0[ni], acc[mi][ni], 0, 0, 0);
#pragma unroll
    for (int i = 0; i < 4; ++i) a0[i] = a1[i];
#pragma unroll
    for (int j = 0; j < 2; ++j) b0[j] = b1[j];
  }
#pragma unroll
  for (int mi = 0; mi < 4; ++mi)
#pragma unroll
    for (int ni = 0; ni < 2; ++ni)
      acc[mi][ni] = __builtin_amdgcn_mfma_f32_16x16x32_bf16(a0[mi], b0[ni], acc[mi][ni], 0, 0, 0);

#pragma unroll
  for (int mi = 0; mi < 4; ++mi)
#pragma unroll
    for (int rr = 0; rr < 4; ++rr) {
      int row = rb + mi * 16 + lq * 4 + rr;
      float bi = out_b[row];
#pragma unroll
      for (int ni = 0; ni < 2; ++ni) {
        int col = cb + ni * 16 + lm;
        size_t off = ((size_t)b * CC + row) * NSP + col;
        out[off] = acc[mi][ni][rr] + x[off] + bi;
      }
    }
}

extern "C" void kernel_launch(void* const* d_in, const int* in_sizes, int n_in,
                              void* d_out, int out_size, void* d_ws, size_t ws_size,
                              hipStream_t stream) {
  const float* x       = (const float*)d_in[0];
  const float* g_w     = (const float*)d_in[1];
  const float* g_b     = (const float*)d_in[2];
  const float* theta_w = (const float*)d_in[3];
  const float* theta_b = (const float*)d_in[4];
  const float* phi_w   = (const float*)d_in[5];
  const float* phi_b   = (const float*)d_in[6];
  const float* out_w   = (const float*)d_in[7];
  const float* out_b   = (const float*)d_in[8];
  float* wsf = (float*)d_ws;
  unsigned short* wsh = (unsigned short*)(wsf + F_WEND);
  float* out = (float*)d_out;

  kW<<<dim3(128), dim3(256), 0, stream>>>(g_w, theta_w, phi_w, out_w, wsh);
  kP<<<dim3(512), dim3(256), 0, stream>>>(g_b, theta_b, phi_b, x, wsh);
  kS<<<dim3(64), dim3(256), 0, stream>>>(wsh, wsf);
  kR<<<dim3(64), dim3(256), 0, stream>>>(wsf, wsh);
  kW2<<<dim3(16), dim3(256), 0, stream>>>(wsh);
  kD<<<dim3(512), dim3(256), 0, stream>>>(wsh, x, out_b, out);
}